// Round 18
// baseline (85.895 us; speedup 1.0000x reference)
//
#include <hip/hip_runtime.h>

typedef float  f32x4  __attribute__((ext_vector_type(4)));
typedef short  s16x8  __attribute__((ext_vector_type(8)));
typedef short  s16x4  __attribute__((ext_vector_type(4)));

__device__ __forceinline__ unsigned short f2bf(float f) {
    unsigned int u = __float_as_uint(f);
    return (unsigned short)((u + 0x7FFFu + ((u >> 16) & 1u)) >> 16);
}

__device__ __forceinline__ s16x8 cvt8(f32x4 a, f32x4 b) {
    union { unsigned int u[4]; s16x8 v; } r;
    asm("v_cvt_pk_bf16_f32 %0, %1, %2" : "=v"(r.u[0]) : "v"(a[0]), "v"(a[1]));
    asm("v_cvt_pk_bf16_f32 %0, %1, %2" : "=v"(r.u[1]) : "v"(a[2]), "v"(a[3]));
    asm("v_cvt_pk_bf16_f32 %0, %1, %2" : "=v"(r.u[2]) : "v"(b[0]), "v"(b[1]));
    asm("v_cvt_pk_bf16_f32 %0, %1, %2" : "=v"(r.u[3]) : "v"(b[2]), "v"(b[3]));
    return r.v;
}

// lgkm-only barrier (vmcnt stays in flight)
__device__ __forceinline__ void lds_barrier() {
    asm volatile("s_waitcnt lgkmcnt(0)" ::: "memory");
    __builtin_amdgcn_s_barrier();
    asm volatile("" ::: "memory");
}

// ---------------------------------------------------------------------------
// Kernel 0: wt3 = FRAGMENT-MAJOR bf16 weights (verified R9/R11/R12/R17).
// Fragment (n16, k32) = one wave's exact MFMA B-operand (64 lanes x 16B):
// value = W_sel[k][n&127], n = n16*16 + (lane&15),
// k = k32*32 + (lane>>4)*8 + j; byte = (n16*32 + k32)*1024 + lane*16 + j*2.
// k32-contiguous: a flat 32-step register pipeline walks B with +1024 steps.
// ---------------------------------------------------------------------------
__global__ void prep_wt(const float* __restrict__ Wq,
                        const float* __restrict__ Wk,
                        const float* __restrict__ Wv,
                        unsigned char* __restrict__ wt3) {
    int n = blockIdx.x;                       // 0..383
    const float* W = (n < 128) ? Wq : ((n < 256) ? Wk : Wv);
    int h = n & 127;
    int n16 = n >> 4, lmn = n & 15;
    for (int k = threadIdx.x; k < 1024; k += blockDim.x) {
        unsigned short v = f2bf(W[(size_t)k * 128 + h]);
        int k32 = k >> 5, rem = k & 31;
        int l4_ = rem >> 3, j = rem & 7;
        int lane = l4_ * 16 + lmn;
        size_t off = (size_t)(n16 * 32 + k32) * 1024 + lane * 16 + j * 2;
        *(unsigned short*)(wt3 + off) = v;
    }
}

// ---------------------------------------------------------------------------
// Kernel 1: QKV GEMM — R11 structure with BK=128 (8 tiles): the per-tile
// fixed-overhead probe.  14 variants pin at 67-76us; model = per-CU VMEM
// bytes (1.28MB at ~11.7 B/cy) + per-tile fixed cost x 16.  Halving tile
// count halves the second term while bytes stay constant.
// BM=128, BN=384 (x read once), grid 256, 8 waves 1M x 8N (acc[8][3]).
// A: 2x32KB LDS dbuf, bf16 [128 rows][256B], chunk-XOR swizzle
// ((cIdx)^(row&7))*16 — 2-way max conflicts (free).  A f32 regs loaded a
// FULL tile ahead (8 f32x4/thread), published via 4 ds_write_b128; ONE
// lgkm-only barrier per tile (8 total).  B: wave-private fragment-major
// regs, flat 32-step rolling pipeline (bqE/bqO), issue 1 substep ahead
// (~500cy >> L2 latency), compiler-counted waits, barrier-independent.
// Outputs: Q,K bf16 [B*T][128]; V transposed bf16 [B][128][256].
// ---------------------------------------------------------------------------
__global__ __launch_bounds__(512, 2) void qkv_gemm(
    const float* __restrict__ x,
    const unsigned char* __restrict__ wt3,
    unsigned short* __restrict__ qo,
    unsigned short* __restrict__ ko,
    unsigned short* __restrict__ vto) {

    __shared__ char smem[65536];              // A: 2 x [128][256B] swizzled

    const int tid = threadIdx.x;
    const int bm  = blockIdx.x;               // 0..255 (M tiles of 128)
    const int lane = tid & 63, wid = tid >> 6;
    const int lm = lane & 15, l4 = lane >> 4;

    f32x4 acc[8][3];
#pragma unroll
    for (int i = 0; i < 8; ++i)
#pragma unroll
        for (int j = 0; j < 3; ++j) acc[i][j] = (f32x4)0.f;

    // ---- A staging: thread -> row tid>>2, f32 cols (tid&3)*32 .. +31 ----
    const int ar = tid >> 2;                  // 0..127
    const int qd = tid & 3;                   // quarter
    const float* xp = x + (size_t)(bm * 128 + ar) * 1024 + qd * 32;
    int awb[4];                               // ds_write byte offsets (chunk w)
#pragma unroll
    for (int w = 0; w < 4; ++w)
        awb[w] = ar * 256 + (((qd * 4 + w) ^ (ar & 7)) << 4);

    // ---- B fragment pointers (wave-private; cols wid*48..+47) ----
    const unsigned char* wbq[3];
#pragma unroll
    for (int ni = 0; ni < 3; ++ni)
        wbq[ni] = wt3 + (size_t)(wid * 3 + ni) * 32768 + (size_t)lane * 16;

    int arow[8];
#pragma unroll
    for (int mi = 0; mi < 8; ++mi) arow[mi] = mi * 16 + lm;

    f32x4 pa[8];
    s16x8 bqE[3], bqO[3];

#define ALOAD(T)                                                               \
    do {                                                                       \
        const float* _xq = xp + (T) * 128;                                     \
        _Pragma("unroll")                                                      \
        for (int i = 0; i < 8; ++i) pa[i] = *(const f32x4*)(_xq + i * 4);      \
    } while (0)

#define APUB(WB)                                                               \
    do {                                                                       \
        _Pragma("unroll")                                                      \
        for (int w = 0; w < 4; ++w)                                            \
            *(s16x8*)(smem + (WB) + awb[w]) = cvt8(pa[2 * w], pa[2 * w + 1]);  \
    } while (0)

#define BISSUE(DST, U)                                                         \
    do {                                                                       \
        _Pragma("unroll")                                                      \
        for (int ni = 0; ni < 3; ++ni)                                         \
            (DST)[ni] = *(const s16x8*)(wbq[ni] + (size_t)(U) * 1024);         \
    } while (0)

    // substep: 8 af reads (2 rows at a time) + 24 MFMA with BQ
#define SUBSTEP(RB, U4, BQ)                                                    \
    do {                                                                       \
        _Pragma("unroll")                                                      \
        for (int mp = 0; mp < 4; ++mp) {                                       \
            int r0 = arow[mp * 2], r1 = arow[mp * 2 + 1];                      \
            s16x8 a0 = *(const s16x8*)(smem + (RB) + r0 * 256 +                \
                        ((((U4) * 4 + l4) ^ (r0 & 7)) << 4));                  \
            s16x8 a1 = *(const s16x8*)(smem + (RB) + r1 * 256 +                \
                        ((((U4) * 4 + l4) ^ (r1 & 7)) << 4));                  \
            _Pragma("unroll")                                                  \
            for (int ni = 0; ni < 3; ++ni) {                                   \
                acc[mp * 2][ni] = __builtin_amdgcn_mfma_f32_16x16x32_bf16(     \
                    a0, (BQ)[ni], acc[mp * 2][ni], 0, 0, 0);                   \
                acc[mp * 2 + 1][ni] = __builtin_amdgcn_mfma_f32_16x16x32_bf16( \
                    a1, (BQ)[ni], acc[mp * 2 + 1][ni], 0, 0, 0);               \
            }                                                                  \
        }                                                                      \
    } while (0)

    // ---- prologue: A(0)->buf0, pa=A(1), bqE=B(k32=0) ----
    ALOAD(0);
    APUB(0);                                  // compiler waits pa loads
    ALOAD(1);
    BISSUE(bqE, 0);
    lds_barrier();

#pragma unroll
    for (int T = 0; T < 8; ++T) {
        const int rb = (T & 1) * 32768;
        const int wb = rb ^ 32768;
        // substep 0: consume E(4T), issue O(4T+1); publish A(T+1)
        BISSUE(bqO, 4 * T + 1);
        if (T < 7) APUB(wb);
        SUBSTEP(rb, 0, bqE);
        // substep 1: consume O, issue E(4T+2); reload pa = A(T+2)
        BISSUE(bqE, 4 * T + 2);
        if (T < 6) ALOAD(T + 2);
        SUBSTEP(rb, 1, bqO);
        // substep 2: consume E, issue O(4T+3)
        BISSUE(bqO, 4 * T + 3);
        SUBSTEP(rb, 2, bqE);
        // substep 3: consume O, issue E(4T+4)
        if (T < 7) BISSUE(bqE, 4 * T + 4);
        SUBSTEP(rb, 3, bqO);
        if (T < 7) lds_barrier();
    }

#undef ALOAD
#undef APUB
#undef BISSUE
#undef SUBSTEP

    // ---- epilogue (layout verified R6-R17) ----
#pragma unroll
    for (int mi = 0; mi < 8; ++mi) {
        int m0 = bm * 128 + mi * 16 + l4 * 4;  // global row (j adds 0..3)
#pragma unroll
        for (int ni = 0; ni < 3; ++ni) {
            int nb  = wid * 48 + ni * 16;
            int mat = nb >> 7;                 // 0=Q 1=K 2=V
            int col = (nb & 127) + lm;
            if (mat == 2) {
                int bb = m0 >> 8, tt = m0 & 255;
                s16x4 w4;
#pragma unroll
                for (int j = 0; j < 4; ++j) w4[j] = (short)f2bf(acc[mi][ni][j]);
                *(s16x4*)(vto + ((size_t)bb * 128 + col) * 256 + tt) = w4;
            } else {
                unsigned short* dst = (mat == 0) ? qo : ko;
#pragma unroll
                for (int j = 0; j < 4; ++j)
                    dst[(size_t)(m0 + j) * 128 + col] = f2bf(acc[mi][ni][j]);
            }
        }
    }
}

// ---------------------------------------------------------------------------
// Kernel 2: causal attention (unchanged, verified; ~7µs).
// ---------------------------------------------------------------------------
__global__ __launch_bounds__(512) void attn(
    const unsigned short* __restrict__ q,
    const unsigned short* __restrict__ k,
    const unsigned short* __restrict__ vt,
    float* __restrict__ out) {

    __shared__ char pbuf[65536];               // 8 waves x [16][256] bf16

    const int tid = threadIdx.x, wid = tid >> 6, lane = tid & 63;
    const int lm = lane & 15, l4 = lane >> 4;
    const int b = blockIdx.x >> 1, qt = blockIdx.x & 1;
    const int qbase = qt << 7;
    const int t0 = qbase + wid * 16;
    const int nfrags = (qbase + 128) >> 4;
    const int nkf    = (qbase + 128) >> 5;

    const unsigned short* qrow = q + (size_t)(b * 256 + t0 + lm) * 128 + l4 * 8;
    s16x8 qf[4];
#pragma unroll
    for (int kf = 0; kf < 4; ++kf) qf[kf] = *(const s16x8*)(qrow + kf * 32);

    f32x4 sacc[16];
#pragma unroll
    for (int i = 0; i < 16; ++i) sacc[i] = (f32x4)0.f;

    const unsigned short* kbase = k + (size_t)(b * 256) * 128 + l4 * 8;
#pragma unroll
    for (int nf = 0; nf < 16; ++nf) {
        if (nf < nfrags) {
#pragma unroll
            for (int kf = 0; kf < 4; ++kf) {
                s16x8 a = *(const s16x8*)(kbase + (size_t)(nf * 16 + lm) * 128 + kf * 32);
                sacc[nf] = __builtin_amdgcn_mfma_f32_16x16x32_bf16(a, qf[kf], sacc[nf], 0, 0, 0);
            }
        }
    }

    const float scale = 0.08838834764831845f;  // 1/sqrt(128)
    const int tg = t0 + lm;
    float mx = -1e30f;
#pragma unroll
    for (int nf = 0; nf < 16; ++nf) {
        if (nf < nfrags) {
#pragma unroll
            for (int j = 0; j < 4; ++j) {
                int kv = nf * 16 + l4 * 4 + j;
                float s = sacc[nf][j] * scale;
                s = (kv > tg) ? -1e30f : s;
                sacc[nf][j] = s;
                mx = fmaxf(mx, s);
            }
        }
    }
    mx = fmaxf(mx, __shfl_xor(mx, 16));
    mx = fmaxf(mx, __shfl_xor(mx, 32));
    float sum = 0.f;
#pragma unroll
    for (int nf = 0; nf < 16; ++nf) {
        if (nf < nfrags) {
#pragma unroll
            for (int j = 0; j < 4; ++j) {
                float p = __expf(sacc[nf][j] - mx);
                sacc[nf][j] = p;
                sum += p;
            }
        }
    }
    sum += __shfl_xor(sum, 16);
    sum += __shfl_xor(sum, 32);
    float rinv = 1.0f / sum;

    char* pw = pbuf + wid * 8192 + lm * 512;
#pragma unroll
    for (int nf = 0; nf < 16; ++nf) {
        if (nf < nfrags) {
            s16x4 w;
#pragma unroll
            for (int j = 0; j < 4; ++j) w[j] = (short)f2bf(sacc[nf][j] * rinv);
            *(s16x4*)(pw + ((nf * 32 + l4 * 8) ^ ((lm & 7) << 4))) = w;
        }
    }
    asm volatile("s_waitcnt lgkmcnt(0)" ::: "memory");

    f32x4 oacc[8];
#pragma unroll
    for (int i = 0; i < 8; ++i) oacc[i] = (f32x4)0.f;

    const unsigned short* vbase = vt + (size_t)b * 32768 + l4 * 8;
#pragma unroll
    for (int kvf = 0; kvf < 8; ++kvf) {
        if (kvf < nkf) {
            s16x8 pf = *(const s16x8*)(pbuf + wid * 8192 + lm * 512 +
                        ((kvf * 64 + l4 * 16) ^ ((lm & 7) << 4)));
#pragma unroll
            for (int hf = 0; hf < 8; ++hf) {
                s16x8 a = *(const s16x8*)(vbase + (size_t)(hf * 16 + lm) * 256 + kvf * 32);
                oacc[hf] = __builtin_amdgcn_mfma_f32_16x16x32_bf16(a, pf, oacc[hf], 0, 0, 0);
            }
        }
    }

    float* ob = out + (size_t)(b * 256 + t0 + lm) * 128 + l4 * 4;
#pragma unroll
    for (int hf = 0; hf < 8; ++hf)
        *(f32x4*)(ob + hf * 16) = oacc[hf];
}

// ---------------------------------------------------------------------------
extern "C" void kernel_launch(void* const* d_in, const int* in_sizes, int n_in,
                              void* d_out, int out_size, void* d_ws, size_t ws_size,
                              hipStream_t stream) {
    const float* x  = (const float*)d_in[0];
    const float* Wq = (const float*)d_in[1];
    const float* Wk = (const float*)d_in[2];
    const float* Wv = (const float*)d_in[3];
    float* out = (float*)d_out;

    char* ws = (char*)d_ws;
    unsigned char*  wt = (unsigned char*)(ws);                     // 786432 B (fragment-major)
    unsigned short* qb = (unsigned short*)(ws + 786432);
    unsigned short* kb = (unsigned short*)(ws + 786432 + 8388608);
    unsigned short* vb = (unsigned short*)(ws + 786432 + 2 * 8388608);

    prep_wt<<<384, 256, 0, stream>>>(Wq, Wk, Wv, wt);
    qkv_gemm<<<256, 512, 0, stream>>>(x, wt, qb, kb, vb);
    attn<<<256, 512, 0, stream>>>(qb, kb, vb, out);
}